// Round 1
// baseline (927.150 us; speedup 1.0000x reference)
//
#include <hip/hip_runtime.h>
#include <hip/hip_bf16.h>
#include <math.h>

#define INF 3.0e38f
#define KTILE 4096

// ---------------------------------------------------------------- 3-NN ----
// One thread per unknown point; block caches the batch's known points (as
// float4 x,y,z,pad) in LDS, scans all of them maintaining top-3.
__global__ __launch_bounds__(256) void knn3_kernel(
    const float* __restrict__ unk, const float* __restrict__ kn,
    const int* __restrict__ ucnt, const int* __restrict__ kcnt,
    int B, int N, float* __restrict__ dist, int* __restrict__ idxo)
{
    __shared__ float kxyz[KTILE][4];

    int p = blockIdx.x * 256 + threadIdx.x;
    if (p >= N) return;

    // batch id of this unknown point (B is tiny, e.g. 4)
    int cum = 0, bb = 0;
    for (int i = 0; i < B; i++) {
        int c = ucnt[i];
        if (p >= cum && p < cum + c) bb = i;
        cum += c;
    }
    int kstart = 0;
    for (int i = 0; i < bb; i++) kstart += kcnt[i];
    int kend = kstart + kcnt[bb];

    float ux = unk[p * 3 + 0], uy = unk[p * 3 + 1], uz = unk[p * 3 + 2];

    float d0 = INF, d1 = INF, d2v = INF;
    int i0 = 0, i1 = 0, i2 = 0;

    for (int t0 = kstart; t0 < kend; t0 += KTILE) {
        int cnt = min(KTILE, kend - t0);
        __syncthreads();
        // coalesced load of cnt*3 floats, scatter into padded float4 slots
        for (int f = threadIdx.x; f < cnt * 3; f += 256) {
            int pt = f / 3, comp = f - pt * 3;
            kxyz[pt][comp] = kn[(t0 + pt) * 3 + comp];
        }
        __syncthreads();

        for (int j = 0; j < cnt; j++) {
            float4 k4 = *(const float4*)kxyz[j];   // broadcast read
            float dx = ux - k4.x, dy = uy - k4.y, dz = uz - k4.z;
            float d = dx * dx + dy * dy + dz * dz;
            if (d < d2v) {
                int gj = t0 + j;
                if (d < d1) {
                    d2v = d1; i2 = i1;
                    if (d < d0) { d1 = d0; i1 = i0; d0 = d; i0 = gj; }
                    else        { d1 = d;  i1 = gj; }
                } else { d2v = d; i2 = gj; }
            }
        }
    }
    dist[p * 3 + 0] = d0;  dist[p * 3 + 1] = d1;  dist[p * 3 + 2] = d2v;
    idxo[p * 3 + 0] = i0;  idxo[p * 3 + 1] = i1;  idxo[p * 3 + 2] = i2;
}

// -------------------------------------------------- interpolate (C2=256) --
// 64 lanes cover one point's 256 channels (float4 each); 4 points per block.
__global__ __launch_bounds__(256) void interp_kernel(
    const float* __restrict__ dist, const int* __restrict__ idxv,
    const float* __restrict__ kf, float* __restrict__ outv, int N)
{
    int t = blockIdx.x * 256 + threadIdx.x;
    int p = t >> 6;
    int c4 = t & 63;
    if (p >= N) return;

    float dd0 = dist[p * 3 + 0], dd1 = dist[p * 3 + 1], dd2 = dist[p * 3 + 2];
    float w0 = 1.0f / (dd0 + 1e-8f);
    float w1 = 1.0f / (dd1 + 1e-8f);
    float w2 = 1.0f / (dd2 + 1e-8f);
    float r = 1.0f / (w0 + w1 + w2);
    w0 *= r; w1 *= r; w2 *= r;

    int j0 = idxv[p * 3 + 0], j1 = idxv[p * 3 + 1], j2 = idxv[p * 3 + 2];
    float4 v0 = ((const float4*)(kf + (size_t)j0 * 256))[c4];
    float4 v1 = ((const float4*)(kf + (size_t)j1 * 256))[c4];
    float4 v2 = ((const float4*)(kf + (size_t)j2 * 256))[c4];

    float4 o;
    o.x = v0.x * w0 + v1.x * w1 + v2.x * w2;
    o.y = v0.y * w0 + v1.y * w1 + v2.y * w2;
    o.z = v0.z * w0 + v1.z * w1 + v2.z * w2;
    o.w = v0.w * w0 + v1.w * w1 + v2.w * w2;
    ((float4*)(outv + (size_t)p * 256))[c4] = o;
}

// -------------------------------------------------------------- fp32 GEMM --
// C[N,256] = A[N,K] * W^T, W is [Cout,K] row-major.
// MODE 0: A = [interp | unknown_feats] (K=384, split at k=256)
// MODE 1: A = relu(h1*scale + shift) read from A0 (K=256)
#define BM 128
#define BN 128
#define BK 16

template <int MODE>
__global__ __launch_bounds__(256) void gemm_kernel(
    const float* __restrict__ A0, const float* __restrict__ A1,
    const float* __restrict__ Bw,
    const float* __restrict__ scale, const float* __restrict__ shift,
    float* __restrict__ C, int N, int K, int Cout)
{
    __shared__ float As[BK][BM + 4];
    __shared__ float Bs[BK][BN + 4];

    int tid = threadIdx.x;
    int ty = tid >> 4;          // 0..15  (row group)
    int tx = tid & 15;          // 0..15  (col group)
    int bm = blockIdx.x * BM;
    int bn = blockIdx.y * BN;

    float acc[8][8];
#pragma unroll
    for (int i = 0; i < 8; i++)
#pragma unroll
        for (int j = 0; j < 8; j++) acc[i][j] = 0.0f;

    int nkb = K / BK;
    for (int kb = 0; kb < nkb; kb++) {
        int k0 = kb * BK;
        // stage A: 128x16 floats = 512 float4, 2 per thread
#pragma unroll
        for (int i = 0; i < 2; i++) {
            int id = tid + i * 256;
            int row = id >> 2;
            int kq = (id & 3) * 4;
            int gk = k0 + kq;
            int gr = bm + row;
            float4 v;
            if (MODE == 0) {
                if (gk < 256) v = *(const float4*)(A0 + (size_t)gr * 256 + gk);
                else          v = *(const float4*)(A1 + (size_t)gr * 128 + (gk - 256));
            } else {
                v = *(const float4*)(A0 + (size_t)gr * 256 + gk);
                float4 s4 = *(const float4*)(scale + gk);
                float4 t4 = *(const float4*)(shift + gk);
                v.x = fmaxf(v.x * s4.x + t4.x, 0.0f);
                v.y = fmaxf(v.y * s4.y + t4.y, 0.0f);
                v.z = fmaxf(v.z * s4.z + t4.z, 0.0f);
                v.w = fmaxf(v.w * s4.w + t4.w, 0.0f);
            }
            As[kq + 0][row] = v.x;
            As[kq + 1][row] = v.y;
            As[kq + 2][row] = v.z;
            As[kq + 3][row] = v.w;
        }
        // stage B: Bs[k][n] = Bw[(bn+n)*K + k0 + k]
#pragma unroll
        for (int i = 0; i < 2; i++) {
            int id = tid + i * 256;
            int col = id >> 2;
            int kq = (id & 3) * 4;
            float4 v = *(const float4*)(Bw + (size_t)(bn + col) * K + k0 + kq);
            Bs[kq + 0][col] = v.x;
            Bs[kq + 1][col] = v.y;
            Bs[kq + 2][col] = v.z;
            Bs[kq + 3][col] = v.w;
        }
        __syncthreads();

#pragma unroll
        for (int k = 0; k < BK; k++) {
            float a[8], b[8];
            *(float4*)&a[0] = *(const float4*)&As[k][ty * 8];
            *(float4*)&a[4] = *(const float4*)&As[k][ty * 8 + 4];
            *(float4*)&b[0] = *(const float4*)&Bs[k][tx * 8];
            *(float4*)&b[4] = *(const float4*)&Bs[k][tx * 8 + 4];
#pragma unroll
            for (int i = 0; i < 8; i++)
#pragma unroll
                for (int j = 0; j < 8; j++)
                    acc[i][j] += a[i] * b[j];
        }
        __syncthreads();
    }

    // store C (row stride Cout)
#pragma unroll
    for (int i = 0; i < 8; i++) {
        int gr = bm + ty * 8 + i;
        float* cp = C + (size_t)gr * Cout + bn + tx * 8;
        float4 v0 = { acc[i][0], acc[i][1], acc[i][2], acc[i][3] };
        float4 v1 = { acc[i][4], acc[i][5], acc[i][6], acc[i][7] };
        *(float4*)(cp + 0) = v0;
        *(float4*)(cp + 4) = v1;
    }
}

// ----------------------------------------------------------- BN statistics --
__global__ __launch_bounds__(256) void bn_stats_kernel(
    const float* __restrict__ h, int N, float* __restrict__ sum,
    float* __restrict__ sumsq)
{
    int c4 = threadIdx.x & 63;     // float4 column group (4 channels)
    int rl = threadIdx.x >> 6;     // 0..3
    float4 s = {0, 0, 0, 0}, q = {0, 0, 0, 0};
    for (int r = blockIdx.x * 4 + rl; r < N; r += gridDim.x * 4) {
        float4 v = ((const float4*)(h + (size_t)r * 256))[c4];
        s.x += v.x; s.y += v.y; s.z += v.z; s.w += v.w;
        q.x += v.x * v.x; q.y += v.y * v.y; q.z += v.z * v.z; q.w += v.w * v.w;
    }
    __shared__ float4 ls[4][64];
    __shared__ float4 lq[4][64];
    ls[rl][c4] = s;
    lq[rl][c4] = q;
    __syncthreads();
    if (threadIdx.x < 64) {
        float4 S = {0, 0, 0, 0}, Q = {0, 0, 0, 0};
#pragma unroll
        for (int i = 0; i < 4; i++) {
            S.x += ls[i][c4].x; S.y += ls[i][c4].y; S.z += ls[i][c4].z; S.w += ls[i][c4].w;
            Q.x += lq[i][c4].x; Q.y += lq[i][c4].y; Q.z += lq[i][c4].z; Q.w += lq[i][c4].w;
        }
        atomicAdd(&sum[c4 * 4 + 0], S.x);
        atomicAdd(&sum[c4 * 4 + 1], S.y);
        atomicAdd(&sum[c4 * 4 + 2], S.z);
        atomicAdd(&sum[c4 * 4 + 3], S.w);
        atomicAdd(&sumsq[c4 * 4 + 0], Q.x);
        atomicAdd(&sumsq[c4 * 4 + 1], Q.y);
        atomicAdd(&sumsq[c4 * 4 + 2], Q.z);
        atomicAdd(&sumsq[c4 * 4 + 3], Q.w);
    }
}

__global__ void bn_finalize_kernel(
    const float* __restrict__ sum, const float* __restrict__ sumsq,
    const float* __restrict__ g, const float* __restrict__ bta, float invN,
    float* __restrict__ scale, float* __restrict__ shift)
{
    int c = threadIdx.x;   // 256 channels
    float mean = sum[c] * invN;
    float var = sumsq[c] * invN - mean * mean;   // biased, matches torch BN
    float sc = g[c] * rsqrtf(var + 1e-5f);
    scale[c] = sc;
    shift[c] = bta[c] - mean * sc;
}

// --------------------------------------------------------- final activation --
__global__ __launch_bounds__(256) void final_act_kernel(
    const float* __restrict__ h2, const float* __restrict__ scale,
    const float* __restrict__ shift, float* __restrict__ out, int total4)
{
    int i = blockIdx.x * 256 + threadIdx.x;
    if (i >= total4) return;
    int c4 = i & 63;
    float4 v = ((const float4*)h2)[i];
    float4 s = ((const float4*)scale)[c4];
    float4 t = ((const float4*)shift)[c4];
    float4 o;
    o.x = fmaxf(v.x * s.x + t.x, 0.0f);
    o.y = fmaxf(v.y * s.y + t.y, 0.0f);
    o.z = fmaxf(v.z * s.z + t.z, 0.0f);
    o.w = fmaxf(v.w * s.w + t.w, 0.0f);
    ((float4*)out)[i] = o;
}

// ------------------------------------------------------------------ launch --
extern "C" void kernel_launch(void* const* d_in, const int* in_sizes, int n_in,
                              void* d_out, int out_size, void* d_ws, size_t ws_size,
                              hipStream_t stream)
{
    const float* unknown = (const float*)d_in[0];
    const int*   ucnt    = (const int*)d_in[1];
    const float* known   = (const float*)d_in[2];
    const int*   kcnt    = (const int*)d_in[3];
    const float* ufeat   = (const float*)d_in[4];
    const float* kfeat   = (const float*)d_in[5];
    const float* W1      = (const float*)d_in[6];
    const float* g1      = (const float*)d_in[7];
    const float* b1      = (const float*)d_in[8];
    const float* W2      = (const float*)d_in[9];
    const float* g2      = (const float*)d_in[10];
    const float* b2      = (const float*)d_in[11];

    int N = in_sizes[0] / 3;        // 65536
    int B = in_sizes[1];            // 4
    // K1 = 384, C2 = 256, Cout = 256 (fixed by reference shapes)

    char* ws = (char*)d_ws;
    float* dist  = (float*)ws;                       // N*3 floats
    int*   idxb  = (int*)(ws + (size_t)N * 3 * 4);   // N*3 ints
    float* stats = (float*)(ws + (size_t)N * 3 * 8); // 8*256 floats
    float* sum1 = stats,        *sq1 = stats + 256;
    float* scale1 = stats + 512, *shift1 = stats + 768;
    float* sum2 = stats + 1024, *sq2 = stats + 1280;
    float* scale2 = stats + 1536, *shift2 = stats + 1792;
    size_t big_off = ((size_t)N * 3 * 8 + 8 * 256 * 4 + 255) & ~(size_t)255;
    float* interp = (float*)(ws + big_off);          // N*256 floats; reused as h2
    float* h2 = interp;
    float* h1 = (float*)d_out;                       // h1 lives in d_out

    hipMemsetAsync(stats, 0, 8 * 256 * 4, stream);

    knn3_kernel<<<(N + 255) / 256, 256, 0, stream>>>(unknown, known, ucnt, kcnt,
                                                     B, N, dist, idxb);
    interp_kernel<<<(N * 64 + 255) / 256, 256, 0, stream>>>(dist, idxb, kfeat,
                                                            interp, N);
    gemm_kernel<0><<<dim3(N / BM, 256 / BN), 256, 0, stream>>>(
        interp, ufeat, W1, nullptr, nullptr, h1, N, 384, 256);
    bn_stats_kernel<<<512, 256, 0, stream>>>(h1, N, sum1, sq1);
    bn_finalize_kernel<<<1, 256, 0, stream>>>(sum1, sq1, g1, b1, 1.0f / N,
                                              scale1, shift1);
    gemm_kernel<1><<<dim3(N / BM, 256 / BN), 256, 0, stream>>>(
        h1, nullptr, W2, scale1, shift1, h2, N, 256, 256);
    bn_stats_kernel<<<512, 256, 0, stream>>>(h2, N, sum2, sq2);
    bn_finalize_kernel<<<1, 256, 0, stream>>>(sum2, sq2, g2, b2, 1.0f / N,
                                              scale2, shift2);
    final_act_kernel<<<(N * 64 + 255) / 256, 256, 0, stream>>>(
        h2, scale2, shift2, (float*)d_out, N * 64);
}